// Round 7
// baseline (745.287 us; speedup 1.0000x reference)
//
#include <hip/hip_runtime.h>
#include <hip/hip_bf16.h>

typedef unsigned short u16;
typedef unsigned int   u32;
typedef __bf16 bf16x8 __attribute__((ext_vector_type(8)));
typedef float  f32x4  __attribute__((ext_vector_type(4)));
typedef u32    u32x4  __attribute__((ext_vector_type(4)));

#define TRI_TOTAL 131328  // sum_{n=0}^{511} (n+1)

__device__ __forceinline__ float b2f(u16 u) {
    return __builtin_bit_cast(float, ((u32)u) << 16);
}
__device__ __forceinline__ u16 f2b(float f) {  // RNE f32->bf16
    u32 u = __builtin_bit_cast(u32, f);
    return (u16)((u + 0x7fffu + ((u >> 16) & 1u)) >> 16);
}

// ---------------- LayerNorm -> xn (bf16) ----------------
__global__ void __launch_bounds__(256) ln_kernel(const float* __restrict__ x,
                                                 const float* __restrict__ g,
                                                 const float* __restrict__ b,
                                                 u16* __restrict__ xn) {
    int n = blockIdx.x, t = threadIdx.x;
    float v = x[n * 256 + t];
    __shared__ float red[4];
    float s = v;
    #pragma unroll
    for (int o = 32; o >= 1; o >>= 1) s += __shfl_xor(s, o);
    if ((t & 63) == 0) red[t >> 6] = s;
    __syncthreads();
    float mu = (red[0] + red[1] + red[2] + red[3]) * (1.0f / 256.0f);
    float d = v - mu;
    __syncthreads();
    float s2 = d * d;
    #pragma unroll
    for (int o = 32; o >= 1; o >>= 1) s2 += __shfl_xor(s2, o);
    if ((t & 63) == 0) red[t >> 6] = s2;
    __syncthreads();
    float var = (red[0] + red[1] + red[2] + red[3]) * (1.0f / 256.0f);
    float y = d * rsqrtf(var + 1e-5f) * g[t] + b[t];
    xn[n * 256 + t] = f2b(y);
}

// ---------------- Per-relative-index projections (v7) ----------------
// Q/V: qd[r,m] = xn[m] @ W[r], needed m in [0, 512-r).  Stored at tri(r+m)+m.
// K:   kd[r,pos] = xn[pos] @ Wk[r], needed pos in [511-r, 512).
//      Stored at tri(pos) + (pos-(511-r)).
// v7 = R5 dataflow (per-k-step A loads from L2; zero-conflict swizzled Wl;
// NO register A-tiles) but 512-thread blocks: 8 waves share one 32 KB Wl
// -> up to 24-32 waves/CU instead of 20, doubling latency-hiding TLP.
__global__ void __launch_bounds__(512, 6) proj_kernel(
        const u16* __restrict__ xn,
        const float* __restrict__ Wq, const float* __restrict__ Wk,
        const float* __restrict__ Wv,
        u16* __restrict__ Qa, u16* __restrict__ Ka, u16* __restrict__ Va) {
    __shared__ u16 Wl[64 * 256];   // [col][k] bf16, 32-bank XOR-swizzled rows

    int bid = blockIdx.x;
    int which = bid >> 11;          // 0=Q,1=K,2=V (2048 blocks each)
    int rr = bid & 2047;
    int r  = (which == 1) ? (511 - (rr >> 2)) : (rr >> 2);  // heavy first
    int cs = rr & 3;
    const float* W = (which == 0) ? Wq : ((which == 1) ? Wk : Wv);
    u16* Out       = (which == 0) ? Qa : ((which == 1) ? Ka : Va);
    int rows  = (which == 1) ? (r + 1) : (512 - r);
    int pbase = (which == 1) ? (511 - r) : 0;   // xn position = pbase + ml
    int nbase = (which == 1) ? (511 - r) : r;   // attn row n = nbase + ml

    int t = threadIdx.x;
    int c0 = cs * 64;

    // stage W[r][:, c0:c0+64] -> Wl[c][k] bf16 (transposed), swizzled.
    // 512 threads: c = t&63, k-eighth = t>>6 (32 k's each).
    {
        int c  = t & 63;
        int kh = (t >> 6) << 5;     // 0,32,...,224
        const float* wp = W + ((size_t)r << 16) + (size_t)(c0 + c);
        char* wrow = (char*)Wl + c * 512;
        int sw = (c & 31) << 4;
        #pragma unroll
        for (int kk = 0; kk < 4; ++kk) {
            int kbase = kh + kk * 8;
            u32x4 tmp;
            #pragma unroll
            for (int i = 0; i < 4; ++i) {
                float flo = wp[(size_t)(kbase + 2 * i) << 8];
                float fhi = wp[(size_t)(kbase + 2 * i + 1) << 8];
                tmp[i] = (u32)f2b(flo) | ((u32)f2b(fhi) << 16);
            }
            *reinterpret_cast<u32x4*>(wrow + ((kbase * 2) ^ sw)) = tmp;
        }
    }
    __syncthreads();                // Wl ready; no more barriers this block

    int wv  = t >> 6;               // 0..7
    int wr  = wv >> 1;              // row quarter: 0..3
    int wc  = wv & 1;               // col half: 0/1
    int L   = t & 63;
    int l15 = L & 15, l4 = L >> 4;
    int rbase = wr * 32;            // rows [rbase, rbase+32) of the 128-row tile
    int cbase = wc * 32;            // cols [cbase, cbase+32) of the 64-col slice

    for (int m0 = 0; m0 < rows; m0 += 128) {
        f32x4 acc00 = {}, acc01 = {}, acc10 = {}, acc11 = {};
        #pragma unroll
        for (int ks = 0; ks < 8; ++ks) {
            int kb = ks * 64 + l4 * 16;   // byte offset of lane's 8 bf16
            bf16x8 a0, a1, b0, b1;
            {
                int ml0 = m0 + rbase + l15;
                int g0 = pbase + ml0;       if (g0 > 511) g0 = 511;
                int g1 = pbase + ml0 + 16;  if (g1 > 511) g1 = 511;
                a0 = *reinterpret_cast<const bf16x8*>(
                    (const char*)xn + (size_t)g0 * 512 + kb);
                a1 = *reinterpret_cast<const bf16x8*>(
                    (const char*)xn + (size_t)g1 * 512 + kb);
            }
            {
                int col0 = cbase + l15;
                int col1 = col0 + 16;
                b0 = *reinterpret_cast<const bf16x8*>(
                    (const char*)Wl + col0 * 512 + (kb ^ ((col0 & 31) << 4)));
                b1 = *reinterpret_cast<const bf16x8*>(
                    (const char*)Wl + col1 * 512 + (kb ^ ((col1 & 31) << 4)));
            }
            acc00 = __builtin_amdgcn_mfma_f32_16x16x32_bf16(a0, b0, acc00, 0, 0, 0);
            acc01 = __builtin_amdgcn_mfma_f32_16x16x32_bf16(a0, b1, acc01, 0, 0, 0);
            acc10 = __builtin_amdgcn_mfma_f32_16x16x32_bf16(a1, b0, acc10, 0, 0, 0);
            acc11 = __builtin_amdgcn_mfma_f32_16x16x32_bf16(a1, b1, acc11, 0, 0, 0);
        }
        // store to packed attention layout
        #pragma unroll
        for (int rf = 0; rf < 2; ++rf) {
            #pragma unroll
            for (int j = 0; j < 4; ++j) {
                int ml = m0 + rbase + rf * 16 + l4 * 4 + j;
                if (ml < rows) {
                    int nout = nbase + ml;
                    size_t prow = (size_t)(nout * (nout + 1) / 2) + (size_t)ml;
                    u16* op = Out + prow * 256 + c0 + cbase + l15;
                    f32x4 va = rf ? acc10 : acc00;
                    f32x4 vb = rf ? acc11 : acc01;
                    op[0]  = f2b(va[j]);
                    op[16] = f2b(vb[j]);
                }
            }
        }
    }
}

// ---------------- per-row attention ----------------
// Block = one query row n. Band rows tri(n)..tri(n)+n hold per-pair q,k,v.
__global__ void __launch_bounds__(256) attn_kernel(const u16* __restrict__ Qa,
                                                   const u16* __restrict__ Ka,
                                                   const u16* __restrict__ Va,
                                                   float* __restrict__ ao) {
    int n = blockIdx.x, t = threadIdx.x;
    __shared__ float pbuf[512 * 9];   // [m][h] padded pitch 9
    __shared__ float linv[8];
    int band = n + 1;
    size_t rb = (size_t)(n * (n + 1) / 2);

    // scores: thread = (m-inner, h)
    int h = t & 7, mi = t >> 3;
    for (int m0 = 0; m0 < band; m0 += 32) {
        int m = m0 + mi;
        float d = -1e30f;
        if (m < band) {
            const char* qp = (const char*)Qa + (rb + m) * 512 + h * 64;
            const char* kp = (const char*)Ka + (rb + m) * 512 + h * 64;
            float acc = 0.f;
            #pragma unroll
            for (int cch = 0; cch < 4; ++cch) {
                u32x4 qv = *reinterpret_cast<const u32x4*>(qp + cch * 16);
                u32x4 kv = *reinterpret_cast<const u32x4*>(kp + cch * 16);
                #pragma unroll
                for (int i = 0; i < 4; ++i) {
                    float ql = __builtin_bit_cast(float, qv[i] << 16);
                    float qh = __builtin_bit_cast(float, qv[i] & 0xffff0000u);
                    float kl = __builtin_bit_cast(float, kv[i] << 16);
                    float kh = __builtin_bit_cast(float, kv[i] & 0xffff0000u);
                    acc += ql * kl + qh * kh;
                }
            }
            d = acc * 0.17677669529663687f;  // 1/sqrt(32)
        }
        pbuf[m * 9 + h] = d;
    }
    __syncthreads();

    // softmax per head: wave wv handles heads wv and wv+4
    int wv = t >> 6, L = t & 63;
    for (int s = 0; s < 2; ++s) {
        int hh = wv + s * 4;
        float mx = -1e30f;
        for (int m = L; m < band; m += 64) mx = fmaxf(mx, pbuf[m * 9 + hh]);
        #pragma unroll
        for (int o = 32; o >= 1; o >>= 1) mx = fmaxf(mx, __shfl_xor(mx, o));
        float sum = 0.f;
        for (int m = L; m < band; m += 64) {
            float p = __expf(pbuf[m * 9 + hh] - mx);
            pbuf[m * 9 + hh] = p;
            sum += p;
        }
        #pragma unroll
        for (int o = 32; o >= 1; o >>= 1) sum += __shfl_xor(sum, o);
        if (L == 0) linv[hh] = 1.0f / sum;
    }
    __syncthreads();

    // PV: thread = output channel t = h*32+e
    int h2 = t >> 5;
    const char* vp = (const char*)Va + rb * 512 + (size_t)t * 2;
    const float* pb = pbuf + h2;
    float a0 = 0, a1 = 0, a2 = 0, a3 = 0;
    int m = 0;
    for (; m + 4 <= band; m += 4) {
        a0 += pb[(m + 0) * 9] * b2f(*(const u16*)(vp + (size_t)(m + 0) * 512));
        a1 += pb[(m + 1) * 9] * b2f(*(const u16*)(vp + (size_t)(m + 1) * 512));
        a2 += pb[(m + 2) * 9] * b2f(*(const u16*)(vp + (size_t)(m + 2) * 512));
        a3 += pb[(m + 3) * 9] * b2f(*(const u16*)(vp + (size_t)(m + 3) * 512));
    }
    for (; m < band; ++m)
        a0 += pb[m * 9] * b2f(*(const u16*)(vp + (size_t)m * 512));
    ao[n * 256 + t] = ((a0 + a1) + (a2 + a3)) * linv[h2];
}

// ---------------- output projection ----------------
__global__ void __launch_bounds__(256) outproj_kernel(const float* __restrict__ ao,
                                                      const float* __restrict__ Wo,
                                                      const float* __restrict__ bo,
                                                      float* __restrict__ out) {
    int n = blockIdx.x, e = threadIdx.x;
    const float* a = ao + n * 256;
    float c0 = bo[e], c1 = 0, c2 = 0, c3 = 0;
    for (int c = 0; c < 256; c += 4) {
        c0 += a[c + 0] * Wo[(c + 0) * 256 + e];
        c1 += a[c + 1] * Wo[(c + 1) * 256 + e];
        c2 += a[c + 2] * Wo[(c + 2) * 256 + e];
        c3 += a[c + 3] * Wo[(c + 3) * 256 + e];
    }
    out[n * 256 + e] = (c0 + c1) + (c2 + c3);
}

extern "C" void kernel_launch(void* const* d_in, const int* in_sizes, int n_in,
                              void* d_out, int out_size, void* d_ws, size_t ws_size,
                              hipStream_t stream) {
    const float* x     = (const float*)d_in[0];
    const float* Wq    = (const float*)d_in[1];
    const float* Wk    = (const float*)d_in[2];
    const float* Wv    = (const float*)d_in[3];
    const float* gamma = (const float*)d_in[4];
    const float* beta  = (const float*)d_in[5];
    const float* Wo    = (const float*)d_in[6];
    const float* bo    = (const float*)d_in[7];
    float* out = (float*)d_out;

    char* ws = (char*)d_ws;
    u16* xn = (u16*)ws;
    size_t off = (size_t)512 * 256 * 2;
    u16* Qa = (u16*)(ws + off); off += (size_t)TRI_TOTAL * 256 * 2;
    u16* Ka = (u16*)(ws + off); off += (size_t)TRI_TOTAL * 256 * 2;
    u16* Va = (u16*)(ws + off); off += (size_t)TRI_TOTAL * 256 * 2;
    float* ao = (float*)(ws + off);

    ln_kernel<<<512, 256, 0, stream>>>(x, gamma, beta, xn);
    proj_kernel<<<6144, 512, 0, stream>>>(xn, Wq, Wk, Wv, Qa, Ka, Va);
    attn_kernel<<<512, 256, 0, stream>>>(Qa, Ka, Va, ao);
    outproj_kernel<<<512, 256, 0, stream>>>(ao, Wo, bo, out);
}

// Round 8
// 307.465 us; speedup vs baseline: 2.4240x; 2.4240x over previous
//
#include <hip/hip_runtime.h>
#include <hip/hip_bf16.h>

typedef unsigned short u16;
typedef unsigned int   u32;
typedef __bf16 bf16x8 __attribute__((ext_vector_type(8)));
typedef float  f32x4  __attribute__((ext_vector_type(4)));
typedef u32    u32x4  __attribute__((ext_vector_type(4)));

#define TRI_TOTAL 131328  // sum_{n=0}^{511} (n+1)

__device__ __forceinline__ float b2f(u16 u) {
    return __builtin_bit_cast(float, ((u32)u) << 16);
}
__device__ __forceinline__ u16 f2b(float f) {  // RNE f32->bf16
    u32 u = __builtin_bit_cast(u32, f);
    return (u16)((u + 0x7fffu + ((u >> 16) & 1u)) >> 16);
}

// ---------------- LayerNorm -> xn (bf16) ----------------
__global__ void __launch_bounds__(256) ln_kernel(const float* __restrict__ x,
                                                 const float* __restrict__ g,
                                                 const float* __restrict__ b,
                                                 u16* __restrict__ xn) {
    int n = blockIdx.x, t = threadIdx.x;
    float v = x[n * 256 + t];
    __shared__ float red[4];
    float s = v;
    #pragma unroll
    for (int o = 32; o >= 1; o >>= 1) s += __shfl_xor(s, o);
    if ((t & 63) == 0) red[t >> 6] = s;
    __syncthreads();
    float mu = (red[0] + red[1] + red[2] + red[3]) * (1.0f / 256.0f);
    float d = v - mu;
    __syncthreads();
    float s2 = d * d;
    #pragma unroll
    for (int o = 32; o >= 1; o >>= 1) s2 += __shfl_xor(s2, o);
    if ((t & 63) == 0) red[t >> 6] = s2;
    __syncthreads();
    float var = (red[0] + red[1] + red[2] + red[3]) * (1.0f / 256.0f);
    float y = d * rsqrtf(var + 1e-5f) * g[t] + b[t];
    xn[n * 256 + t] = f2b(y);
}

// ---------------- Per-relative-index projections (v8) ----------------
// Q/V: qd[r,m] = xn[m] @ W[r], needed m in [0, 512-r).  Stored at tri(r+m)+m.
// K:   kd[r,pos] = xn[pos] @ Wk[r], needed pos in [511-r, 512).
//      Stored at tri(pos) + (pos-(511-r)).
// v8 = R5's conflict-free structure + R2's fat wave tile: 32 rows x 64 cols
// per wave (2 inline A-loads, 4 B ds_reads, 8 MFMA per k-step), 4 waves
// row-stacked -> 128-row m-tiles. Plain launch_bounds(256): the only
// spill-free configs (R3/R5) used exactly this; forced bounds spilled (R6/R7).
__global__ void __launch_bounds__(256) proj_kernel(
        const u16* __restrict__ xn,
        const float* __restrict__ Wq, const float* __restrict__ Wk,
        const float* __restrict__ Wv,
        u16* __restrict__ Qa, u16* __restrict__ Ka, u16* __restrict__ Va) {
    __shared__ u16 Wl[64 * 256];   // [col][k] bf16, 32-bank XOR-swizzled rows

    int bid = blockIdx.x;
    int which = bid >> 11;          // 0=Q,1=K,2=V (2048 blocks each)
    int rr = bid & 2047;
    int r  = (which == 1) ? (511 - (rr >> 2)) : (rr >> 2);  // heavy first
    int cs = rr & 3;
    const float* W = (which == 0) ? Wq : ((which == 1) ? Wk : Wv);
    u16* Out       = (which == 0) ? Qa : ((which == 1) ? Ka : Va);
    int rows  = (which == 1) ? (r + 1) : (512 - r);
    int pbase = (which == 1) ? (511 - r) : 0;   // xn position = pbase + ml
    int nbase = (which == 1) ? (511 - r) : r;   // attn row n = nbase + ml

    int t = threadIdx.x;
    int c0 = cs * 64;

    // stage W[r][:, c0:c0+64] -> Wl[c][k] bf16 (transposed), swizzled.
    {
        int c  = t & 63;
        int kh = (t >> 6) << 6;     // 0,64,128,192
        const float* wp = W + ((size_t)r << 16) + (size_t)(c0 + c);
        char* wrow = (char*)Wl + c * 512;
        int sw = (c & 31) << 4;
        #pragma unroll
        for (int kk = 0; kk < 8; ++kk) {
            int kbase = kh + kk * 8;
            u32x4 tmp;
            #pragma unroll
            for (int i = 0; i < 4; ++i) {
                float flo = wp[(size_t)(kbase + 2 * i) << 8];
                float fhi = wp[(size_t)(kbase + 2 * i + 1) << 8];
                tmp[i] = (u32)f2b(flo) | ((u32)f2b(fhi) << 16);
            }
            *reinterpret_cast<u32x4*>(wrow + ((kbase * 2) ^ sw)) = tmp;
        }
    }
    __syncthreads();                // Wl ready; no more barriers this block

    int wv  = t >> 6;               // 0..3, row-stacked
    int L   = t & 63;
    int l15 = L & 15, l4 = L >> 4;
    int rbase = wv * 32;            // wave rows [rbase, rbase+32) of 128-row tile
    const char* wb = (const char*)Wl;
    int cA = l15, cB = 16 + l15, cC = 32 + l15, cD = 48 + l15;
    int swA = (cA & 31) << 4, swB = (cB & 31) << 4;
    int swC = (cC & 31) << 4, swD = (cD & 31) << 4;

    for (int m0 = 0; m0 < rows; m0 += 128) {
        int mlo = m0 + rbase + l15;
        int g0 = pbase + mlo;       if (g0 > 511) g0 = 511;
        int g1 = pbase + mlo + 16;  if (g1 > 511) g1 = 511;
        const char* s0 = (const char*)xn + (size_t)g0 * 512 + l4 * 16;
        const char* s1 = (const char*)xn + (size_t)g1 * 512 + l4 * 16;

        f32x4 acL0 = {}, acL1 = {}, acL2 = {}, acL3 = {};
        f32x4 acH0 = {}, acH1 = {}, acH2 = {}, acH3 = {};
        #pragma unroll
        for (int ks = 0; ks < 8; ++ks) {
            int kb = ks * 64 + l4 * 16;   // byte offset of lane's 8 bf16
            bf16x8 a0 = *reinterpret_cast<const bf16x8*>(s0 + ks * 64);
            bf16x8 a1 = *reinterpret_cast<const bf16x8*>(s1 + ks * 64);
            bf16x8 b0 = *reinterpret_cast<const bf16x8*>(wb + cA * 512 + (kb ^ swA));
            bf16x8 b1 = *reinterpret_cast<const bf16x8*>(wb + cB * 512 + (kb ^ swB));
            bf16x8 b2 = *reinterpret_cast<const bf16x8*>(wb + cC * 512 + (kb ^ swC));
            bf16x8 b3 = *reinterpret_cast<const bf16x8*>(wb + cD * 512 + (kb ^ swD));
            acL0 = __builtin_amdgcn_mfma_f32_16x16x32_bf16(a0, b0, acL0, 0, 0, 0);
            acH0 = __builtin_amdgcn_mfma_f32_16x16x32_bf16(a1, b0, acH0, 0, 0, 0);
            acL1 = __builtin_amdgcn_mfma_f32_16x16x32_bf16(a0, b1, acL1, 0, 0, 0);
            acH1 = __builtin_amdgcn_mfma_f32_16x16x32_bf16(a1, b1, acH1, 0, 0, 0);
            acL2 = __builtin_amdgcn_mfma_f32_16x16x32_bf16(a0, b2, acL2, 0, 0, 0);
            acH2 = __builtin_amdgcn_mfma_f32_16x16x32_bf16(a1, b2, acH2, 0, 0, 0);
            acL3 = __builtin_amdgcn_mfma_f32_16x16x32_bf16(a0, b3, acL3, 0, 0, 0);
            acH3 = __builtin_amdgcn_mfma_f32_16x16x32_bf16(a1, b3, acH3, 0, 0, 0);
        }

        // store to packed attention layout
        #pragma unroll
        for (int j = 0; j < 4; ++j) {
            int ml = m0 + rbase + l4 * 4 + j;
            if (ml < rows) {
                int nout = nbase + ml;
                size_t prow = (size_t)(nout * (nout + 1) / 2) + (size_t)ml;
                u16* op = Out + prow * 256 + c0 + l15;
                op[0]  = f2b(acL0[j]);
                op[16] = f2b(acL1[j]);
                op[32] = f2b(acL2[j]);
                op[48] = f2b(acL3[j]);
            }
            int ml2 = ml + 16;
            if (ml2 < rows) {
                int nout = nbase + ml2;
                size_t prow = (size_t)(nout * (nout + 1) / 2) + (size_t)ml2;
                u16* op = Out + prow * 256 + c0 + l15;
                op[0]  = f2b(acH0[j]);
                op[16] = f2b(acH1[j]);
                op[32] = f2b(acH2[j]);
                op[48] = f2b(acH3[j]);
            }
        }
    }
}

// ---------------- per-row attention ----------------
// Block = one query row n. Band rows tri(n)..tri(n)+n hold per-pair q,k,v.
__global__ void __launch_bounds__(256) attn_kernel(const u16* __restrict__ Qa,
                                                   const u16* __restrict__ Ka,
                                                   const u16* __restrict__ Va,
                                                   float* __restrict__ ao) {
    int n = blockIdx.x, t = threadIdx.x;
    __shared__ float pbuf[512 * 9];   // [m][h] padded pitch 9
    __shared__ float linv[8];
    int band = n + 1;
    size_t rb = (size_t)(n * (n + 1) / 2);

    // scores: thread = (m-inner, h)
    int h = t & 7, mi = t >> 3;
    for (int m0 = 0; m0 < band; m0 += 32) {
        int m = m0 + mi;
        float d = -1e30f;
        if (m < band) {
            const char* qp = (const char*)Qa + (rb + m) * 512 + h * 64;
            const char* kp = (const char*)Ka + (rb + m) * 512 + h * 64;
            float acc = 0.f;
            #pragma unroll
            for (int cch = 0; cch < 4; ++cch) {
                u32x4 qv = *reinterpret_cast<const u32x4*>(qp + cch * 16);
                u32x4 kv = *reinterpret_cast<const u32x4*>(kp + cch * 16);
                #pragma unroll
                for (int i = 0; i < 4; ++i) {
                    float ql = __builtin_bit_cast(float, qv[i] << 16);
                    float qh = __builtin_bit_cast(float, qv[i] & 0xffff0000u);
                    float kl = __builtin_bit_cast(float, kv[i] << 16);
                    float kh = __builtin_bit_cast(float, kv[i] & 0xffff0000u);
                    acc += ql * kl + qh * kh;
                }
            }
            d = acc * 0.17677669529663687f;  // 1/sqrt(32)
        }
        pbuf[m * 9 + h] = d;
    }
    __syncthreads();

    // softmax per head: wave wv handles heads wv and wv+4
    int wv = t >> 6, L = t & 63;
    for (int s = 0; s < 2; ++s) {
        int hh = wv + s * 4;
        float mx = -1e30f;
        for (int m = L; m < band; m += 64) mx = fmaxf(mx, pbuf[m * 9 + hh]);
        #pragma unroll
        for (int o = 32; o >= 1; o >>= 1) mx = fmaxf(mx, __shfl_xor(mx, o));
        float sum = 0.f;
        for (int m = L; m < band; m += 64) {
            float p = __expf(pbuf[m * 9 + hh] - mx);
            pbuf[m * 9 + hh] = p;
            sum += p;
        }
        #pragma unroll
        for (int o = 32; o >= 1; o >>= 1) sum += __shfl_xor(sum, o);
        if (L == 0) linv[hh] = 1.0f / sum;
    }
    __syncthreads();

    // PV: thread = output channel t = h*32+e
    int h2 = t >> 5;
    const char* vp = (const char*)Va + rb * 512 + (size_t)t * 2;
    const float* pb = pbuf + h2;
    float a0 = 0, a1 = 0, a2 = 0, a3 = 0;
    int m = 0;
    for (; m + 4 <= band; m += 4) {
        a0 += pb[(m + 0) * 9] * b2f(*(const u16*)(vp + (size_t)(m + 0) * 512));
        a1 += pb[(m + 1) * 9] * b2f(*(const u16*)(vp + (size_t)(m + 1) * 512));
        a2 += pb[(m + 2) * 9] * b2f(*(const u16*)(vp + (size_t)(m + 2) * 512));
        a3 += pb[(m + 3) * 9] * b2f(*(const u16*)(vp + (size_t)(m + 3) * 512));
    }
    for (; m < band; ++m)
        a0 += pb[m * 9] * b2f(*(const u16*)(vp + (size_t)m * 512));
    ao[n * 256 + t] = ((a0 + a1) + (a2 + a3)) * linv[h2];
}

// ---------------- output projection ----------------
__global__ void __launch_bounds__(256) outproj_kernel(const float* __restrict__ ao,
                                                      const float* __restrict__ Wo,
                                                      const float* __restrict__ bo,
                                                      float* __restrict__ out) {
    int n = blockIdx.x, e = threadIdx.x;
    const float* a = ao + n * 256;
    float c0 = bo[e], c1 = 0, c2 = 0, c3 = 0;
    for (int c = 0; c < 256; c += 4) {
        c0 += a[c + 0] * Wo[(c + 0) * 256 + e];
        c1 += a[c + 1] * Wo[(c + 1) * 256 + e];
        c2 += a[c + 2] * Wo[(c + 2) * 256 + e];
        c3 += a[c + 3] * Wo[(c + 3) * 256 + e];
    }
    out[n * 256 + e] = (c0 + c1) + (c2 + c3);
}

extern "C" void kernel_launch(void* const* d_in, const int* in_sizes, int n_in,
                              void* d_out, int out_size, void* d_ws, size_t ws_size,
                              hipStream_t stream) {
    const float* x     = (const float*)d_in[0];
    const float* Wq    = (const float*)d_in[1];
    const float* Wk    = (const float*)d_in[2];
    const float* Wv    = (const float*)d_in[3];
    const float* gamma = (const float*)d_in[4];
    const float* beta  = (const float*)d_in[5];
    const float* Wo    = (const float*)d_in[6];
    const float* bo    = (const float*)d_in[7];
    float* out = (float*)d_out;

    char* ws = (char*)d_ws;
    u16* xn = (u16*)ws;
    size_t off = (size_t)512 * 256 * 2;
    u16* Qa = (u16*)(ws + off); off += (size_t)TRI_TOTAL * 256 * 2;
    u16* Ka = (u16*)(ws + off); off += (size_t)TRI_TOTAL * 256 * 2;
    u16* Va = (u16*)(ws + off); off += (size_t)TRI_TOTAL * 256 * 2;
    float* ao = (float*)(ws + off);

    ln_kernel<<<512, 256, 0, stream>>>(x, gamma, beta, xn);
    proj_kernel<<<6144, 256, 0, stream>>>(xn, Wq, Wk, Wv, Qa, Ka, Va);
    attn_kernel<<<512, 256, 0, stream>>>(Qa, Ka, Va, ao);
    outproj_kernel<<<512, 256, 0, stream>>>(ao, Wo, bo, out);
}

// Round 9
// 274.015 us; speedup vs baseline: 2.7199x; 1.1221x over previous
//
#include <hip/hip_runtime.h>
#include <hip/hip_bf16.h>

typedef unsigned short u16;
typedef unsigned int   u32;
typedef __bf16 bf16x8 __attribute__((ext_vector_type(8)));
typedef float  f32x4  __attribute__((ext_vector_type(4)));
typedef u32    u32x4  __attribute__((ext_vector_type(4)));
typedef u32    u32x2  __attribute__((ext_vector_type(2)));

#define TRI_TOTAL 131328  // sum_{n=0}^{511} (n+1)

__device__ __forceinline__ float b2f(u16 u) {
    return __builtin_bit_cast(float, ((u32)u) << 16);
}
__device__ __forceinline__ u16 f2b(float f) {  // RNE f32->bf16
    u32 u = __builtin_bit_cast(u32, f);
    return (u16)((u + 0x7fffu + ((u >> 16) & 1u)) >> 16);
}

// ---------------- LayerNorm -> xn (bf16) ----------------
__global__ void __launch_bounds__(256) ln_kernel(const float* __restrict__ x,
                                                 const float* __restrict__ g,
                                                 const float* __restrict__ b,
                                                 u16* __restrict__ xn) {
    int n = blockIdx.x, t = threadIdx.x;
    float v = x[n * 256 + t];
    __shared__ float red[4];
    float s = v;
    #pragma unroll
    for (int o = 32; o >= 1; o >>= 1) s += __shfl_xor(s, o);
    if ((t & 63) == 0) red[t >> 6] = s;
    __syncthreads();
    float mu = (red[0] + red[1] + red[2] + red[3]) * (1.0f / 256.0f);
    float d = v - mu;
    __syncthreads();
    float s2 = d * d;
    #pragma unroll
    for (int o = 32; o >= 1; o >>= 1) s2 += __shfl_xor(s2, o);
    if ((t & 63) == 0) red[t >> 6] = s2;
    __syncthreads();
    float var = (red[0] + red[1] + red[2] + red[3]) * (1.0f / 256.0f);
    float y = d * rsqrtf(var + 1e-5f) * g[t] + b[t];
    xn[n * 256 + t] = f2b(y);
}

// ---------------- Per-relative-index projections (v9) ----------------
// Q/V: qd[r,m] = xn[m] @ W[r], needed m in [0, 512-r).  Stored at tri(r+m)+m.
// K:   kd[r,pos] = xn[pos] @ Wk[r], needed pos in [511-r, 512).
//      Stored at tri(pos) + (pos-(511-r)).
// v9: (a) coalesced dwordx4 W staging (4x MLP for the 402 MB HBM stream);
// (b) LDS-staged A tile (Al 32 KB) so the k-loop is pure ds_read+MFMA --
// no strided global scatters on the critical path; T14 next-tile prefetch
// into 8 named u32x4 regs. Wave tile 16x64, m-tile 64, 2 barriers/tile.
__global__ void __launch_bounds__(256) proj_kernel(
        const u16* __restrict__ xn,
        const float* __restrict__ Wq, const float* __restrict__ Wk,
        const float* __restrict__ Wv,
        u16* __restrict__ Qa, u16* __restrict__ Ka, u16* __restrict__ Va) {
    __shared__ u16 Wl[64 * 256];   // [col][k] bf16, XOR-swizzled rows
    __shared__ u16 Al[64 * 256];   // [row][k] bf16, XOR-swizzled rows

    int bid = blockIdx.x;
    int which = bid >> 11;          // 0=Q,1=K,2=V (2048 blocks each)
    int rr = bid & 2047;
    int r  = (which == 1) ? (511 - (rr >> 2)) : (rr >> 2);  // heavy first
    int cs = rr & 3;
    const float* W = (which == 0) ? Wq : ((which == 1) ? Wk : Wv);
    u16* Out       = (which == 0) ? Qa : ((which == 1) ? Ka : Va);
    int rows  = (which == 1) ? (r + 1) : (512 - r);
    int pbase = (which == 1) ? (511 - r) : 0;   // xn position = pbase + ml
    int nbase = (which == 1) ? (511 - r) : r;   // attn row n = nbase + ml

    int t = threadIdx.x;
    int c0 = cs * 64;

    // ---- A staging state: thread covers (row = it*8 + srow, 16B slot) ----
    int srow   = t >> 5;            // 0..7
    int slot16 = (t & 31) * 16;     // byte slot within row
    char* adp = (char*)Al + srow * 512 + (slot16 ^ (srow << 4));
    u32x4 ar0, ar1, ar2, ar3, ar4, ar5, ar6, ar7;

#define A_LOAD(M0) do {                                                       \
    int gg;                                                                   \
    gg = pbase + (M0) +  0 + srow; if (gg > 511) gg = 511;                    \
    ar0 = *(const u32x4*)((const char*)xn + (size_t)gg * 512 + slot16);       \
    gg = pbase + (M0) +  8 + srow; if (gg > 511) gg = 511;                    \
    ar1 = *(const u32x4*)((const char*)xn + (size_t)gg * 512 + slot16);       \
    gg = pbase + (M0) + 16 + srow; if (gg > 511) gg = 511;                    \
    ar2 = *(const u32x4*)((const char*)xn + (size_t)gg * 512 + slot16);       \
    gg = pbase + (M0) + 24 + srow; if (gg > 511) gg = 511;                    \
    ar3 = *(const u32x4*)((const char*)xn + (size_t)gg * 512 + slot16);       \
    gg = pbase + (M0) + 32 + srow; if (gg > 511) gg = 511;                    \
    ar4 = *(const u32x4*)((const char*)xn + (size_t)gg * 512 + slot16);       \
    gg = pbase + (M0) + 40 + srow; if (gg > 511) gg = 511;                    \
    ar5 = *(const u32x4*)((const char*)xn + (size_t)gg * 512 + slot16);       \
    gg = pbase + (M0) + 48 + srow; if (gg > 511) gg = 511;                    \
    ar6 = *(const u32x4*)((const char*)xn + (size_t)gg * 512 + slot16);       \
    gg = pbase + (M0) + 56 + srow; if (gg > 511) gg = 511;                    \
    ar7 = *(const u32x4*)((const char*)xn + (size_t)gg * 512 + slot16);       \
} while (0)

#define A_WRITE() do {                                                        \
    *(u32x4*)(adp + 0 * 4096) = ar0;                                          \
    *(u32x4*)(adp + 1 * 4096) = ar1;                                          \
    *(u32x4*)(adp + 2 * 4096) = ar2;                                          \
    *(u32x4*)(adp + 3 * 4096) = ar3;                                          \
    *(u32x4*)(adp + 4 * 4096) = ar4;                                          \
    *(u32x4*)(adp + 5 * 4096) = ar5;                                          \
    *(u32x4*)(adp + 6 * 4096) = ar6;                                          \
    *(u32x4*)(adp + 7 * 4096) = ar7;                                          \
} while (0)

    // ---- Wl stage: coalesced dwordx4 loads, swizzled b64 writes ----
    {
        int c4 = (t & 15) * 4;          // 4 consecutive cols
        int kq = t >> 4;                // 0..15 -> k-quad base kq*4, +64/it
        const float* wp = W + ((size_t)r << 16) + c0 + c4 + (size_t)(kq * 4) * 256;
        f32x4 w00 = *(const f32x4*)(wp + 0 * 256);
        f32x4 w01 = *(const f32x4*)(wp + 1 * 256);
        f32x4 w02 = *(const f32x4*)(wp + 2 * 256);
        f32x4 w03 = *(const f32x4*)(wp + 3 * 256);
        f32x4 w10 = *(const f32x4*)(wp + 16384 + 0 * 256);
        f32x4 w11 = *(const f32x4*)(wp + 16384 + 1 * 256);
        f32x4 w12 = *(const f32x4*)(wp + 16384 + 2 * 256);
        f32x4 w13 = *(const f32x4*)(wp + 16384 + 3 * 256);
        f32x4 w20 = *(const f32x4*)(wp + 32768 + 0 * 256);
        f32x4 w21 = *(const f32x4*)(wp + 32768 + 1 * 256);
        f32x4 w22 = *(const f32x4*)(wp + 32768 + 2 * 256);
        f32x4 w23 = *(const f32x4*)(wp + 32768 + 3 * 256);
        f32x4 w30 = *(const f32x4*)(wp + 49152 + 0 * 256);
        f32x4 w31 = *(const f32x4*)(wp + 49152 + 1 * 256);
        f32x4 w32 = *(const f32x4*)(wp + 49152 + 2 * 256);
        f32x4 w33 = *(const f32x4*)(wp + 49152 + 3 * 256);
        A_LOAD(0);                      // first A-tile flies with the W loads
#define WLW(IT, VA, VB, VC, VD) {                                             \
        int kbase = kq * 4 + (IT) * 64;                                       \
        _Pragma("unroll")                                                     \
        for (int i = 0; i < 4; ++i) {                                         \
            int col = c4 + i;                                                 \
            u32 lo = (u32)f2b(VA[i]) | ((u32)f2b(VB[i]) << 16);               \
            u32 hi = (u32)f2b(VC[i]) | ((u32)f2b(VD[i]) << 16);               \
            u32x2 pr; pr[0] = lo; pr[1] = hi;                                 \
            *(u32x2*)((char*)Wl + col * 512 +                                 \
                      ((kbase * 2) ^ ((col & 31) << 4))) = pr;                \
        }                                                                     \
    }
        WLW(0, w00, w01, w02, w03)
        WLW(1, w10, w11, w12, w13)
        WLW(2, w20, w21, w22, w23)
        WLW(3, w30, w31, w32, w33)
#undef WLW
    }
    __syncthreads();                    // Wl ready

    int wv  = t >> 6;                   // 0..3, row-stacked: 16 rows each
    int L   = t & 63;
    int l15 = L & 15, l4 = L >> 4;
    int rbase = wv * 16;
    const char* wb = (const char*)Wl;
    const char* al_row = (const char*)Al + (rbase + l15) * 512;
    int amask = ((rbase + l15) & 7) << 4;
    int cA = l15, cB = 16 + l15, cC = 32 + l15, cD = 48 + l15;
    int swA = (cA & 31) << 4, swB = (cB & 31) << 4;
    int swC = (cC & 31) << 4, swD = (cD & 31) << 4;

    for (int m0 = 0; m0 < rows; m0 += 64) {
        A_WRITE();
        __syncthreads();                // Al ready
        if (m0 + 64 < rows) A_LOAD(m0 + 64);   // T14: issue early

        f32x4 acc0 = {}, acc1 = {}, acc2 = {}, acc3 = {};
#define KS(ks) {                                                              \
        int kb = (ks) * 64 + l4 * 16;                                         \
        bf16x8 a  = *(const bf16x8*)(al_row + (kb ^ amask));                  \
        bf16x8 b0 = *(const bf16x8*)(wb + cA * 512 + (kb ^ swA));             \
        bf16x8 b1 = *(const bf16x8*)(wb + cB * 512 + (kb ^ swB));             \
        bf16x8 b2 = *(const bf16x8*)(wb + cC * 512 + (kb ^ swC));             \
        bf16x8 b3 = *(const bf16x8*)(wb + cD * 512 + (kb ^ swD));             \
        acc0 = __builtin_amdgcn_mfma_f32_16x16x32_bf16(a, b0, acc0, 0, 0, 0); \
        acc1 = __builtin_amdgcn_mfma_f32_16x16x32_bf16(a, b1, acc1, 0, 0, 0); \
        acc2 = __builtin_amdgcn_mfma_f32_16x16x32_bf16(a, b2, acc2, 0, 0, 0); \
        acc3 = __builtin_amdgcn_mfma_f32_16x16x32_bf16(a, b3, acc3, 0, 0, 0); \
    }
        KS(0) KS(1) KS(2) KS(3) KS(4) KS(5) KS(6) KS(7)
#undef KS

        // store to packed attention layout
        #pragma unroll
        for (int j = 0; j < 4; ++j) {
            int ml = m0 + rbase + l4 * 4 + j;
            if (ml < rows) {
                int nout = nbase + ml;
                size_t prow = (size_t)(nout * (nout + 1) / 2) + (size_t)ml;
                u16* op = Out + prow * 256 + c0 + l15;
                op[0]  = f2b(acc0[j]);
                op[16] = f2b(acc1[j]);
                op[32] = f2b(acc2[j]);
                op[48] = f2b(acc3[j]);
            }
        }
        __syncthreads();                // Al fully consumed
    }
#undef A_LOAD
#undef A_WRITE
}

// ---------------- per-row attention ----------------
// Block = one query row n. Band rows tri(n)..tri(n)+n hold per-pair q,k,v.
__global__ void __launch_bounds__(256) attn_kernel(const u16* __restrict__ Qa,
                                                   const u16* __restrict__ Ka,
                                                   const u16* __restrict__ Va,
                                                   float* __restrict__ ao) {
    int n = blockIdx.x, t = threadIdx.x;
    __shared__ float pbuf[512 * 9];   // [m][h] padded pitch 9
    __shared__ float linv[8];
    int band = n + 1;
    size_t rb = (size_t)(n * (n + 1) / 2);

    // scores: thread = (m-inner, h)
    int h = t & 7, mi = t >> 3;
    for (int m0 = 0; m0 < band; m0 += 32) {
        int m = m0 + mi;
        float d = -1e30f;
        if (m < band) {
            const char* qp = (const char*)Qa + (rb + m) * 512 + h * 64;
            const char* kp = (const char*)Ka + (rb + m) * 512 + h * 64;
            float acc = 0.f;
            #pragma unroll
            for (int cch = 0; cch < 4; ++cch) {
                u32x4 qv = *reinterpret_cast<const u32x4*>(qp + cch * 16);
                u32x4 kv = *reinterpret_cast<const u32x4*>(kp + cch * 16);
                #pragma unroll
                for (int i = 0; i < 4; ++i) {
                    float ql = __builtin_bit_cast(float, qv[i] << 16);
                    float qh = __builtin_bit_cast(float, qv[i] & 0xffff0000u);
                    float kl = __builtin_bit_cast(float, kv[i] << 16);
                    float kh = __builtin_bit_cast(float, kv[i] & 0xffff0000u);
                    acc += ql * kl + qh * kh;
                }
            }
            d = acc * 0.17677669529663687f;  // 1/sqrt(32)
        }
        pbuf[m * 9 + h] = d;
    }
    __syncthreads();

    // softmax per head: wave wv handles heads wv and wv+4
    int wv = t >> 6, L = t & 63;
    for (int s = 0; s < 2; ++s) {
        int hh = wv + s * 4;
        float mx = -1e30f;
        for (int m = L; m < band; m += 64) mx = fmaxf(mx, pbuf[m * 9 + hh]);
        #pragma unroll
        for (int o = 32; o >= 1; o >>= 1) mx = fmaxf(mx, __shfl_xor(mx, o));
        float sum = 0.f;
        for (int m = L; m < band; m += 64) {
            float p = __expf(pbuf[m * 9 + hh] - mx);
            pbuf[m * 9 + hh] = p;
            sum += p;
        }
        #pragma unroll
        for (int o = 32; o >= 1; o >>= 1) sum += __shfl_xor(sum, o);
        if (L == 0) linv[hh] = 1.0f / sum;
    }
    __syncthreads();

    // PV: thread = output channel t = h*32+e
    int h2 = t >> 5;
    const char* vp = (const char*)Va + rb * 512 + (size_t)t * 2;
    const float* pb = pbuf + h2;
    float a0 = 0, a1 = 0, a2 = 0, a3 = 0;
    int m = 0;
    for (; m + 4 <= band; m += 4) {
        a0 += pb[(m + 0) * 9] * b2f(*(const u16*)(vp + (size_t)(m + 0) * 512));
        a1 += pb[(m + 1) * 9] * b2f(*(const u16*)(vp + (size_t)(m + 1) * 512));
        a2 += pb[(m + 2) * 9] * b2f(*(const u16*)(vp + (size_t)(m + 2) * 512));
        a3 += pb[(m + 3) * 9] * b2f(*(const u16*)(vp + (size_t)(m + 3) * 512));
    }
    for (; m < band; ++m)
        a0 += pb[m * 9] * b2f(*(const u16*)(vp + (size_t)m * 512));
    ao[n * 256 + t] = ((a0 + a1) + (a2 + a3)) * linv[h2];
}

// ---------------- output projection ----------------
__global__ void __launch_bounds__(256) outproj_kernel(const float* __restrict__ ao,
                                                      const float* __restrict__ Wo,
                                                      const float* __restrict__ bo,
                                                      float* __restrict__ out) {
    int n = blockIdx.x, e = threadIdx.x;
    const float* a = ao + n * 256;
    float c0 = bo[e], c1 = 0, c2 = 0, c3 = 0;
    for (int c = 0; c < 256; c += 4) {
        c0 += a[c + 0] * Wo[(c + 0) * 256 + e];
        c1 += a[c + 1] * Wo[(c + 1) * 256 + e];
        c2 += a[c + 2] * Wo[(c + 2) * 256 + e];
        c3 += a[c + 3] * Wo[(c + 3) * 256 + e];
    }
    out[n * 256 + e] = (c0 + c1) + (c2 + c3);
}

extern "C" void kernel_launch(void* const* d_in, const int* in_sizes, int n_in,
                              void* d_out, int out_size, void* d_ws, size_t ws_size,
                              hipStream_t stream) {
    const float* x     = (const float*)d_in[0];
    const float* Wq    = (const float*)d_in[1];
    const float* Wk    = (const float*)d_in[2];
    const float* Wv    = (const float*)d_in[3];
    const float* gamma = (const float*)d_in[4];
    const float* beta  = (const float*)d_in[5];
    const float* Wo    = (const float*)d_in[6];
    const float* bo    = (const float*)d_in[7];
    float* out = (float*)d_out;

    char* ws = (char*)d_ws;
    u16* xn = (u16*)ws;
    size_t off = (size_t)512 * 256 * 2;
    u16* Qa = (u16*)(ws + off); off += (size_t)TRI_TOTAL * 256 * 2;
    u16* Ka = (u16*)(ws + off); off += (size_t)TRI_TOTAL * 256 * 2;
    u16* Va = (u16*)(ws + off); off += (size_t)TRI_TOTAL * 256 * 2;
    float* ao = (float*)(ws + off);

    ln_kernel<<<512, 256, 0, stream>>>(x, gamma, beta, xn);
    proj_kernel<<<6144, 256, 0, stream>>>(xn, Wq, Wk, Wv, Qa, Ka, Va);
    attn_kernel<<<512, 256, 0, stream>>>(Qa, Ka, Va, ao);
    outproj_kernel<<<512, 256, 0, stream>>>(ao, Wo, bo, out);
}